// Round 8
// baseline (381.573 us; speedup 1.0000x reference)
//
#include <hip/hip_runtime.h>
#include <math.h>

#define NN 100000
#define EE 800000
#define FDIM 64
#define NH 4
#define NEG 0.2f

#define SCAN_BLK 1024
#define SCAN_NBLK 98      // ceil(100000/1024)
#define HIST_BLK 3125     // 800000/256
#define KH_BLK   6250     // 100000/16

// ---------- workspace layout (bytes) ----------
#define OFF_XB     0ull                       // bf16 x: 12.8 MB
#define OFF_HOP1   12800000ull                // bf16 hop1: 12.8 MB
#define OFF_HOP2   25600000ull                // bf16 hop2: 12.8 MB
#define OFF_SSRC   38400000ull                // N*4 fp32
#define OFF_SDST   40000000ull
#define OFF_DEGC   41600000ull                // N int
#define OFF_ROWS   42000000ull
#define OFF_CURS   42400000ull
#define OFF_DEGF   42800000ull
#define OFF_PART   43200000ull
#define OFF_CSRS   43201024ull                // E int
#define OFF_WCAT   46401024ull                // bf16 Wcat[64][128] = 16384 B
#define OFF_BCOMB  46417408ull                // fp32 bc[64]
#define OFF_WT     46417664ull                // bf16 Wt[h][o][k]: 32768 B
#define OFF_WAS    46450432ull                // fp32 waS[4][64]
#define OFF_WAD    46451456ull                // fp32 waD[4][64]
#define WS_NEEDED  46452480ull

typedef __attribute__((ext_vector_type(8))) short bf16x8;
typedef __attribute__((ext_vector_type(4))) float f32x4;

__device__ __forceinline__ float bflo(unsigned int u) { return __uint_as_float(u << 16); }
__device__ __forceinline__ float bfhi(unsigned int u) { return __uint_as_float(u & 0xffff0000u); }
__device__ __forceinline__ unsigned short f2bf(float f) {
    unsigned int u = __float_as_uint(f);
    unsigned int r = u + 0x7fffu + ((u >> 16) & 1u);   // RNE
    return (unsigned short)(r >> 16);
}
__device__ __forceinline__ float lrelu(float x) { return x > 0.f ? x : NEG * x; }

// ---------- P1: Wt repack (blk 0-7) | Wcat/bc (blk 8-23) | degree hist (blk 24+) --
__global__ __launch_bounds__(256) void k_pre(
    const float* __restrict__ Watt, const float* __restrict__ asrc,
    const float* __restrict__ adst, const float* __restrict__ Wg,
    const float* __restrict__ bg, const float* __restrict__ Ww,
    const float* __restrict__ bw, const int* __restrict__ dst,
    unsigned short* __restrict__ Wt, float* __restrict__ waS, float* __restrict__ waD,
    unsigned short* __restrict__ Wcat, float* __restrict__ bc, int* __restrict__ degc)
{
    __shared__ float WcS[64][4];
    const int b = blockIdx.x, t = threadIdx.x;
    if (b < 8) {
        for (int idx = b * 2048 + t; idx < (b + 1) * 2048; idx += 256) {
            const int h = idx >> 12, o = (idx >> 6) & 63, k = idx & 63;
            Wt[idx] = f2bf(Watt[h * 4096 + k * 64 + o]);
        }
        if (b == 0) {
            const int h = t >> 6, i = t & 63;
            float aS = 0.f, aD = 0.f;
            for (int o = 0; o < 64; o++) {
                const float w = Watt[h * 4096 + i * 64 + o];
                aS += w * asrc[h * 64 + o];
                aD += w * adst[h * 64 + o];
            }
            waS[t] = aS;
            waD[t] = aD;
        }
    } else if (b < 24) {
        const int c0 = (b - 8) * 4;
        {
            const int r = t >> 2, ci = t & 3;
            float a = 0.f;
            for (int m = 0; m < 64; m++) a += Wg[r * 64 + m] * Ww[(64 + m) * 64 + c0 + ci];
            WcS[r][ci] = a;
        }
        if (b == 8 && t < 64) {
            float a = bw[t];
            for (int m = 0; m < 64; m++) a += bg[m] * Ww[(64 + m) * 64 + t];
            bc[t] = a;
        }
        __syncthreads();
        for (int idx = t; idx < 512; idx += 256) {
            const int ci = idx >> 7, k = idx & 127;
            const int c = c0 + ci;
            const float v = (k < 64) ? Ww[k * 64 + c] : WcS[k - 64][ci];
            Wcat[c * 128 + k] = f2bf(v);
        }
    } else {
        const int e = (b - 24) * 256 + t;
        if (e < EE) atomicAdd(&degc[dst[e]], 1);
    }
}

// ---------- K3: 3-kernel exclusive scan ----------
__global__ __launch_bounds__(1024) void k_scan_a(const int* __restrict__ degc, int* __restrict__ part) {
    __shared__ int sh[1024];
    int t = threadIdx.x;
    int i = blockIdx.x * SCAN_BLK + t;
    sh[t] = (i < NN) ? degc[i] : 0;
    __syncthreads();
    for (int off = 512; off > 0; off >>= 1) {
        if (t < off) sh[t] += sh[t + off];
        __syncthreads();
    }
    if (t == 0) part[blockIdx.x] = sh[0];
}

__global__ __launch_bounds__(128) void k_scan_b(int* part) {
    __shared__ int sh[128];
    int t = threadIdx.x;
    int v = (t < SCAN_NBLK) ? part[t] : 0;
    sh[t] = v;
    __syncthreads();
    for (int off = 1; off < 128; off <<= 1) {
        int tmp = (t >= off) ? sh[t - off] : 0;
        __syncthreads();
        sh[t] += tmp;
        __syncthreads();
    }
    if (t < SCAN_NBLK) part[t] = sh[t] - v;   // exclusive
}

__global__ __launch_bounds__(1024) void k_scan_c(
    const int* __restrict__ degc, const int* __restrict__ part,
    int* __restrict__ rows, int* __restrict__ curs, float* __restrict__ degf)
{
    __shared__ int sh[1024];
    int t = threadIdx.x;
    int i = blockIdx.x * SCAN_BLK + t;
    int v = (i < NN) ? degc[i] : 0;
    sh[t] = v;
    __syncthreads();
    for (int off = 1; off < 1024; off <<= 1) {
        int tmp = (t >= off) ? sh[t - off] : 0;
        __syncthreads();
        sh[t] += tmp;
        __syncthreads();
    }
    int excl = sh[t] - v + part[blockIdx.x];
    if (i < NN) {
        rows[i] = excl;
        curs[i] = excl;
        degf[i] = (float)max(v, 1);
    }
}

// ---------- P2: CSR scatter (blk < 3125) | xb + scores (blk >= 3125) ------------
__global__ __launch_bounds__(256) void k_mid(
    const int* __restrict__ srcp, const int* __restrict__ dstp,
    int* __restrict__ curs, int* __restrict__ csrs,
    const float* __restrict__ x, const float* __restrict__ waS,
    const float* __restrict__ waD, unsigned short* __restrict__ xb,
    float* __restrict__ ssrc, float* __restrict__ sdst)
{
    __shared__ float xs[16 * 64];
    __shared__ unsigned short xsb[16 * 64];
    __shared__ float wl[2 * 256];
    const int t = threadIdx.x;
    if (blockIdx.x < HIST_BLK) {
        const int e = blockIdx.x * 256 + t;
        if (e < EE) {
            const int d = dstp[e];
            const int pos = atomicAdd(&curs[d], 1);
            csrs[pos] = srcp[e];
        }
        return;
    }
    const int n0 = (blockIdx.x - HIST_BLK) * 16;
    {
        const int r = t >> 4, c4 = (t & 15) * 4;
        const float4 v = *(const float4*)&x[(size_t)(n0 + r) * 64 + c4];
        *(float4*)&xs[r * 64 + c4] = v;
        uint2 p;
        p.x = (unsigned int)f2bf(v.x) | ((unsigned int)f2bf(v.y) << 16);
        p.y = (unsigned int)f2bf(v.z) | ((unsigned int)f2bf(v.w) << 16);
        *(uint2*)&xsb[r * 64 + c4] = p;
        wl[t] = waS[t];
        wl[256 + t] = waD[t];
    }
    __syncthreads();
    if (t < 128) {
        const int r = t >> 3, c8 = (t & 7) * 8;
        const uint4 v = *(const uint4*)&xsb[r * 64 + c8];
        *(uint4*)&xb[(size_t)(n0 + r) * 64 + c8] = v;
    }
    {
        const int nl = t >> 4, hh = (t >> 2) & 3, q = t & 3;
        const float* xr = &xs[nl * 64 + q * 16];
        const float* wS = &wl[hh * 64 + q * 16];
        const float* wD = &wl[256 + hh * 64 + q * 16];
        float pS = 0.f, pD = 0.f;
#pragma unroll
        for (int i = 0; i < 16; i++) { pS += xr[i] * wS[i]; pD += xr[i] * wD[i]; }
        pS += __shfl_xor(pS, 1); pS += __shfl_xor(pS, 2);
        pD += __shfl_xor(pD, 1); pD += __shfl_xor(pD, 2);
        if (q == 0) {
            ssrc[(n0 + nl) * 4 + hh] = pS;
            sdst[(n0 + nl) * 4 + hh] = pD;
        }
    }
}

// ---------- K5 v2: fused attention+hop1; wave = node, 4 slots x 16 col-lanes ----
__global__ __launch_bounds__(256) void k_attn2(
    const unsigned short* __restrict__ xb, const unsigned short* __restrict__ Wt,
    const float* __restrict__ ssrc, const float* __restrict__ sdst,
    const int* __restrict__ rows, const int* __restrict__ degc,
    const float* __restrict__ degf, const int* __restrict__ csrs,
    unsigned short* __restrict__ hop1b, char* __restrict__ outb)
{
    __shared__ unsigned short ysh[4][16][80];   // [head][row][col] bf16, stride 80
    __shared__ float dsh[4][4][66];             // [head][node][col] fp32
    const int t = threadIdx.x;
    const int w = t >> 6, lane = t & 63;
    const int es = lane >> 4, cl = lane & 15;   // edge slot 0..3, col-lane 0..15
    const int n = blockIdx.x * 4 + w;
    const int start = rows[n], cnt = degc[n];
    const float4 sd = *(const float4*)&sdst[n * 4];
    float y0[4] = {0,0,0,0}, y1[4] = {0,0,0,0}, y2[4] = {0,0,0,0};
    float y3[4] = {0,0,0,0}, hp[4] = {0,0,0,0};
    float d0 = 0.f, d1 = 0.f, d2 = 0.f, d3 = 0.f;
    for (int base = 0; base < cnt; base += 4) {
        const int j = base + es;
        const bool valid = j < cnt;
        const int idx = min(start + j, EE - 1);
        const int s = csrs[idx];
        const float4 ss = *(const float4*)&ssrc[s * 4];
        float e0 = __expf(lrelu(ss.x + sd.x));
        float e1 = __expf(lrelu(ss.y + sd.y));
        float e2 = __expf(lrelu(ss.z + sd.z));
        float e3 = __expf(lrelu(ss.w + sd.w));
        float hw = 1.f;
        if (!valid) { e0 = 0.f; e1 = 0.f; e2 = 0.f; e3 = 0.f; hw = 0.f; }
        d0 += e0; d1 += e1; d2 += e2; d3 += e3;
        const uint2 u = *(const uint2*)&xb[(size_t)s * 64 + cl * 4];
        float xv[4];
        xv[0] = bflo(u.x); xv[1] = bfhi(u.x);
        xv[2] = bflo(u.y); xv[3] = bfhi(u.y);
#pragma unroll
        for (int c = 0; c < 4; c++) {
            y0[c] += e0 * xv[c];
            y1[c] += e1 * xv[c];
            y2[c] += e2 * xv[c];
            y3[c] += e3 * xv[c];
            hp[c] += hw * xv[c];
        }
    }
    // reduce over edge-slot bits (lane bits 4,5)
#pragma unroll
    for (int off = 16; off < 64; off <<= 1) {
#pragma unroll
        for (int c = 0; c < 4; c++) {
            y0[c] += __shfl_xor(y0[c], off);
            y1[c] += __shfl_xor(y1[c], off);
            y2[c] += __shfl_xor(y2[c], off);
            y3[c] += __shfl_xor(y3[c], off);
            hp[c] += __shfl_xor(hp[c], off);
        }
        d0 += __shfl_xor(d0, off);
        d1 += __shfl_xor(d1, off);
        d2 += __shfl_xor(d2, off);
        d3 += __shfl_xor(d3, off);
    }
    if (es == 0) {
        const float i0 = (cnt > 0) ? 1.f / d0 : 0.f;
        const float i1 = (cnt > 0) ? 1.f / d1 : 0.f;
        const float i2 = (cnt > 0) ? 1.f / d2 : 0.f;
        const float i3 = (cnt > 0) ? 1.f / d3 : 0.f;
        uint2 p;
        p.x = (unsigned int)f2bf(y0[0]*i0) | ((unsigned int)f2bf(y0[1]*i0) << 16);
        p.y = (unsigned int)f2bf(y0[2]*i0) | ((unsigned int)f2bf(y0[3]*i0) << 16);
        *(uint2*)&ysh[0][w][cl * 4] = p;
        p.x = (unsigned int)f2bf(y1[0]*i1) | ((unsigned int)f2bf(y1[1]*i1) << 16);
        p.y = (unsigned int)f2bf(y1[2]*i1) | ((unsigned int)f2bf(y1[3]*i1) << 16);
        *(uint2*)&ysh[1][w][cl * 4] = p;
        p.x = (unsigned int)f2bf(y2[0]*i2) | ((unsigned int)f2bf(y2[1]*i2) << 16);
        p.y = (unsigned int)f2bf(y2[2]*i2) | ((unsigned int)f2bf(y2[3]*i2) << 16);
        *(uint2*)&ysh[2][w][cl * 4] = p;
        p.x = (unsigned int)f2bf(y3[0]*i3) | ((unsigned int)f2bf(y3[1]*i3) << 16);
        p.y = (unsigned int)f2bf(y3[2]*i3) | ((unsigned int)f2bf(y3[3]*i3) << 16);
        *(uint2*)&ysh[3][w][cl * 4] = p;
        const float iv = 1.f / degf[n];
        p.x = (unsigned int)f2bf(hp[0]*iv) | ((unsigned int)f2bf(hp[1]*iv) << 16);
        p.y = (unsigned int)f2bf(hp[2]*iv) | ((unsigned int)f2bf(hp[3]*iv) << 16);
        *(uint2*)&hop1b[(size_t)n * 64 + cl * 4] = p;
    }
    __syncthreads();
    // MFMA: wave w = head w; A rows 0-3 valid (4-15 garbage -> ignored D rows)
    {
        const int m = lane & 15, quad = lane >> 4;
        const bf16x8 a0 = *(const bf16x8*)&ysh[w][m][quad * 8];
        const bf16x8 a1 = *(const bf16x8*)&ysh[w][m][32 + quad * 8];
        f32x4 acc[4] = {{0.f,0.f,0.f,0.f},{0.f,0.f,0.f,0.f},{0.f,0.f,0.f,0.f},{0.f,0.f,0.f,0.f}};
#pragma unroll
        for (int ot = 0; ot < 4; ot++) {
            const unsigned short* wp = Wt + w * 4096 + (ot * 16 + m) * 64 + quad * 8;
            const bf16x8 b0 = *(const bf16x8*)wp;
            const bf16x8 b1 = *(const bf16x8*)(wp + 32);
            acc[ot] = __builtin_amdgcn_mfma_f32_16x16x32_bf16(a0, b0, acc[ot], 0, 0, 0);
            acc[ot] = __builtin_amdgcn_mfma_f32_16x16x32_bf16(a1, b1, acc[ot], 0, 0, 0);
        }
        if (quad == 0) {
#pragma unroll
            for (int ot = 0; ot < 4; ot++)
#pragma unroll
                for (int r = 0; r < 4; r++)
                    dsh[w][r][ot * 16 + m] = acc[ot][r];
        }
    }
    __syncthreads();
    if (t < 128) {
        const int n2 = t >> 5, c2 = t & 31;
        const float oe = 0.25f * (dsh[0][n2][2*c2]   + dsh[1][n2][2*c2]   + dsh[2][n2][2*c2]   + dsh[3][n2][2*c2]);
        const float oo = 0.25f * (dsh[0][n2][2*c2+1] + dsh[1][n2][2*c2+1] + dsh[2][n2][2*c2+1] + dsh[3][n2][2*c2+1]);
        const unsigned int p = (unsigned int)f2bf(oe) | ((unsigned int)f2bf(oo) << 16);
        *(unsigned int*)(outb + (size_t)(blockIdx.x * 4 + n2) * 256 + c2 * 4) = p;
    }
}

// ---------- K6: second mean hop — 8 lanes per edge row ----------
__global__ __launch_bounds__(256) void k_hop(
    const unsigned short* __restrict__ xin, const int* __restrict__ rows,
    const int* __restrict__ degc, const float* __restrict__ degf,
    const int* __restrict__ csrs, unsigned short* __restrict__ out_b)
{
    const int lane = threadIdx.x & 63;
    const int n = blockIdx.x * 4 + (threadIdx.x >> 6);
    if (n >= NN) return;
    const int start = rows[n], cnt = degc[n];
    const int g = lane >> 3;
    const int c8 = (lane & 7) * 8;
    float a0=0.f,a1=0.f,a2=0.f,a3=0.f,a4=0.f,a5=0.f,a6=0.f,a7=0.f;
    for (int j = g; j < cnt; j += 8) {
        const int s = csrs[start + j];
        const uint4 u = *(const uint4*)&xin[(size_t)s * 64 + c8];
        a0 += bflo(u.x); a1 += bfhi(u.x);
        a2 += bflo(u.y); a3 += bfhi(u.y);
        a4 += bflo(u.z); a5 += bfhi(u.z);
        a6 += bflo(u.w); a7 += bfhi(u.w);
    }
#pragma unroll
    for (int off = 8; off < 64; off <<= 1) {
        a0 += __shfl_xor(a0, off); a1 += __shfl_xor(a1, off);
        a2 += __shfl_xor(a2, off); a3 += __shfl_xor(a3, off);
        a4 += __shfl_xor(a4, off); a5 += __shfl_xor(a5, off);
        a6 += __shfl_xor(a6, off); a7 += __shfl_xor(a7, off);
    }
    if (lane < 8) {
        const float inv = 1.f / degf[n];
        uint4 p;
        p.x = (unsigned int)f2bf(a0 * inv) | ((unsigned int)f2bf(a1 * inv) << 16);
        p.y = (unsigned int)f2bf(a2 * inv) | ((unsigned int)f2bf(a3 * inv) << 16);
        p.z = (unsigned int)f2bf(a4 * inv) | ((unsigned int)f2bf(a5 * inv) << 16);
        p.w = (unsigned int)f2bf(a6 * inv) | ((unsigned int)f2bf(a7 * inv) << 16);
        *(uint4*)&out_b[(size_t)n * 64 + c8] = p;
    }
}

// ---------- K9: MFMA out = cat(localb,hop2b) @ Wcat + bc; 64 nodes/block -------
__global__ __launch_bounds__(256) void k_final(
    const unsigned short* __restrict__ Wcat, const float* __restrict__ bc,
    const unsigned short* __restrict__ hop2b, float* __restrict__ outp)
{
    __shared__ float os[64 * 68];
    __shared__ float bcl[64];
    const int t = threadIdx.x;
    const int n0 = blockIdx.x * 64;
    if (t < 64) bcl[t] = bc[t];
    const int w = t >> 6, lane = t & 63, m = lane & 15, quad = lane >> 4;
    const int node = n0 + w * 16 + m;
    const int nld = min(node, NN - 1);
    const unsigned short* lrow = (const unsigned short*)((const char*)outp + (size_t)nld * 256);
    const unsigned short* grow = &hop2b[(size_t)nld * 64];
    const bf16x8 a0 = *(const bf16x8*)&lrow[quad * 8];
    const bf16x8 a1 = *(const bf16x8*)&lrow[32 + quad * 8];
    const bf16x8 a2 = *(const bf16x8*)&grow[quad * 8];
    const bf16x8 a3 = *(const bf16x8*)&grow[32 + quad * 8];
    f32x4 acc[4] = {{0.f,0.f,0.f,0.f},{0.f,0.f,0.f,0.f},{0.f,0.f,0.f,0.f},{0.f,0.f,0.f,0.f}};
#pragma unroll
    for (int ot = 0; ot < 4; ot++) {
        const unsigned short* wp = Wcat + (ot * 16 + m) * 128 + quad * 8;
        const bf16x8 b0 = *(const bf16x8*)wp;
        const bf16x8 b1 = *(const bf16x8*)(wp + 32);
        const bf16x8 b2 = *(const bf16x8*)(wp + 64);
        const bf16x8 b3 = *(const bf16x8*)(wp + 96);
        acc[ot] = __builtin_amdgcn_mfma_f32_16x16x32_bf16(a0, b0, acc[ot], 0, 0, 0);
        acc[ot] = __builtin_amdgcn_mfma_f32_16x16x32_bf16(a1, b1, acc[ot], 0, 0, 0);
        acc[ot] = __builtin_amdgcn_mfma_f32_16x16x32_bf16(a2, b2, acc[ot], 0, 0, 0);
        acc[ot] = __builtin_amdgcn_mfma_f32_16x16x32_bf16(a3, b3, acc[ot], 0, 0, 0);
    }
    __syncthreads();
#pragma unroll
    for (int ot = 0; ot < 4; ot++)
#pragma unroll
        for (int r = 0; r < 4; r++)
            os[(w * 16 + quad * 4 + r) * 68 + ot * 16 + m] = acc[ot][r] + bcl[ot * 16 + m];
    __syncthreads();
#pragma unroll
    for (int p = 0; p < 4; p++) {
        const int idx = p * 256 + t;
        const int row = idx >> 4, f4 = idx & 15;
        if (n0 + row < NN)
            *(float4*)&outp[(size_t)(n0 + row) * 64 + f4 * 4] = *(const float4*)&os[row * 68 + f4 * 4];
    }
}

extern "C" void kernel_launch(void* const* d_in, const int* in_sizes, int n_in,
                              void* d_out, int out_size, void* d_ws, size_t ws_size,
                              hipStream_t stream)
{
    const float* x    = (const float*)d_in[0];
    const int*   ei   = (const int*)d_in[1];
    const int*   srcp = ei;
    const int*   dstp = ei + EE;
    const float* Watt = (const float*)d_in[2];
    const float* asrc = (const float*)d_in[3];
    const float* adst = (const float*)d_in[4];
    const float* Wg   = (const float*)d_in[5];
    const float* bg   = (const float*)d_in[6];
    const float* Ww   = (const float*)d_in[7];
    const float* bw   = (const float*)d_in[8];
    float* outp = (float*)d_out;

    if (ws_size < WS_NEEDED) return;

    char* ws = (char*)d_ws;
    unsigned short* xb    = (unsigned short*)(ws + OFF_XB);
    unsigned short* hop1b = (unsigned short*)(ws + OFF_HOP1);
    unsigned short* hop2b = (unsigned short*)(ws + OFF_HOP2);
    float* ssrc = (float*)(ws + OFF_SSRC);
    float* sdst = (float*)(ws + OFF_SDST);
    int*   degc = (int*)(ws + OFF_DEGC);
    int*   rows = (int*)(ws + OFF_ROWS);
    int*   curs = (int*)(ws + OFF_CURS);
    float* degf = (float*)(ws + OFF_DEGF);
    int*   part = (int*)(ws + OFF_PART);
    int*   csrs = (int*)(ws + OFF_CSRS);
    unsigned short* Wcat = (unsigned short*)(ws + OFF_WCAT);
    float* bc   = (float*)(ws + OFF_BCOMB);
    unsigned short* Wt = (unsigned short*)(ws + OFF_WT);
    float* waS  = (float*)(ws + OFF_WAS);
    float* waD  = (float*)(ws + OFF_WAD);

    hipMemsetAsync(degc, 0, NN * sizeof(int), stream);
    k_pre<<<24 + HIST_BLK, 256, 0, stream>>>(Watt, asrc, adst, Wg, bg, Ww, bw,
                                             dstp, Wt, waS, waD, Wcat, bc, degc);
    k_scan_a<<<SCAN_NBLK, 1024, 0, stream>>>(degc, part);
    k_scan_b<<<1, 128, 0, stream>>>(part);
    k_scan_c<<<SCAN_NBLK, 1024, 0, stream>>>(degc, part, rows, curs, degf);
    k_mid<<<HIST_BLK + KH_BLK, 256, 0, stream>>>(srcp, dstp, curs, csrs,
                                                 x, waS, waD, xb, ssrc, sdst);
    k_attn2<<<NN / 4, 256, 0, stream>>>(xb, Wt, ssrc, sdst, rows, degc, degf, csrs,
                                        hop1b, (char*)d_out);
    k_hop<<<NN / 4, 256, 0, stream>>>(hop1b, rows, degc, degf, csrs, hop2b);
    k_final<<<(NN + 63) / 64, 256, 0, stream>>>(Wcat, bc, hop2b, outp);
}

// Round 9
// 313.980 us; speedup vs baseline: 1.2153x; 1.2153x over previous
//
#include <hip/hip_runtime.h>
#include <math.h>

#define NN 100000
#define EE 800000
#define FDIM 64
#define NH 4
#define NEG 0.2f

#define SCAN_BLK 1024
#define SCAN_NBLK 98      // ceil(100000/1024)
#define HIST_BLK 3125     // 800000/256
#define KH_BLK   6250     // 100000/16

// ---------- workspace layout (bytes) ----------
#define OFF_XB     0ull                       // bf16 x: 12.8 MB
#define OFF_HOP1   12800000ull                // bf16 hop1: 12.8 MB
#define OFF_HOP2   25600000ull                // bf16 hop2: 12.8 MB
#define OFF_SSRC   38400000ull                // N*4 fp32
#define OFF_SDST   40000000ull
#define OFF_DEGC   41600000ull                // N int
#define OFF_ROWS   42000000ull
#define OFF_CURS   42400000ull
#define OFF_DEGF   42800000ull
#define OFF_PART   43200000ull
#define OFF_CSRS   43201024ull                // E int
#define OFF_WCAT   46401024ull                // bf16 Wcat[64][128] = 16384 B
#define OFF_BCOMB  46417408ull                // fp32 bc[64]
#define OFF_WT     46417664ull                // bf16 Wt[h][o][k]: 32768 B
#define OFF_WAS    46450432ull                // fp32 waS[4][64]
#define OFF_WAD    46451456ull                // fp32 waD[4][64]
#define WS_NEEDED  46452480ull

typedef __attribute__((ext_vector_type(8))) short bf16x8;
typedef __attribute__((ext_vector_type(4))) float f32x4;

__device__ __forceinline__ float bflo(unsigned int u) { return __uint_as_float(u << 16); }
__device__ __forceinline__ float bfhi(unsigned int u) { return __uint_as_float(u & 0xffff0000u); }
__device__ __forceinline__ unsigned short f2bf(float f) {
    unsigned int u = __float_as_uint(f);
    unsigned int r = u + 0x7fffu + ((u >> 16) & 1u);   // RNE
    return (unsigned short)(r >> 16);
}
__device__ __forceinline__ float lrelu(float x) { return x > 0.f ? x : NEG * x; }

// ---------- P1: Wt repack (blk 0-7) | Wcat/bc (blk 8-23) | degree hist (blk 24+) --
__global__ __launch_bounds__(256) void k_pre(
    const float* __restrict__ Watt, const float* __restrict__ asrc,
    const float* __restrict__ adst, const float* __restrict__ Wg,
    const float* __restrict__ bg, const float* __restrict__ Ww,
    const float* __restrict__ bw, const int* __restrict__ dst,
    unsigned short* __restrict__ Wt, float* __restrict__ waS, float* __restrict__ waD,
    unsigned short* __restrict__ Wcat, float* __restrict__ bc, int* __restrict__ degc)
{
    __shared__ float WcS[64][4];
    const int b = blockIdx.x, t = threadIdx.x;
    if (b < 8) {
        for (int idx = b * 2048 + t; idx < (b + 1) * 2048; idx += 256) {
            const int h = idx >> 12, o = (idx >> 6) & 63, k = idx & 63;
            Wt[idx] = f2bf(Watt[h * 4096 + k * 64 + o]);
        }
        if (b == 0) {
            const int h = t >> 6, i = t & 63;
            float aS = 0.f, aD = 0.f;
            for (int o = 0; o < 64; o++) {
                const float w = Watt[h * 4096 + i * 64 + o];
                aS += w * asrc[h * 64 + o];
                aD += w * adst[h * 64 + o];
            }
            waS[t] = aS;
            waD[t] = aD;
        }
    } else if (b < 24) {
        const int c0 = (b - 8) * 4;
        {
            const int r = t >> 2, ci = t & 3;
            float a = 0.f;
            for (int m = 0; m < 64; m++) a += Wg[r * 64 + m] * Ww[(64 + m) * 64 + c0 + ci];
            WcS[r][ci] = a;
        }
        if (b == 8 && t < 64) {
            float a = bw[t];
            for (int m = 0; m < 64; m++) a += bg[m] * Ww[(64 + m) * 64 + t];
            bc[t] = a;
        }
        __syncthreads();
        for (int idx = t; idx < 512; idx += 256) {
            const int ci = idx >> 7, k = idx & 127;
            const int c = c0 + ci;
            const float v = (k < 64) ? Ww[k * 64 + c] : WcS[k - 64][ci];
            Wcat[c * 128 + k] = f2bf(v);
        }
    } else {
        const int e = (b - 24) * 256 + t;
        if (e < EE) atomicAdd(&degc[dst[e]], 1);
    }
}

// ---------- K3: 3-kernel exclusive scan ----------
__global__ __launch_bounds__(1024) void k_scan_a(const int* __restrict__ degc, int* __restrict__ part) {
    __shared__ int sh[1024];
    int t = threadIdx.x;
    int i = blockIdx.x * SCAN_BLK + t;
    sh[t] = (i < NN) ? degc[i] : 0;
    __syncthreads();
    for (int off = 512; off > 0; off >>= 1) {
        if (t < off) sh[t] += sh[t + off];
        __syncthreads();
    }
    if (t == 0) part[blockIdx.x] = sh[0];
}

__global__ __launch_bounds__(128) void k_scan_b(int* part) {
    __shared__ int sh[128];
    int t = threadIdx.x;
    int v = (t < SCAN_NBLK) ? part[t] : 0;
    sh[t] = v;
    __syncthreads();
    for (int off = 1; off < 128; off <<= 1) {
        int tmp = (t >= off) ? sh[t - off] : 0;
        __syncthreads();
        sh[t] += tmp;
        __syncthreads();
    }
    if (t < SCAN_NBLK) part[t] = sh[t] - v;   // exclusive
}

__global__ __launch_bounds__(1024) void k_scan_c(
    const int* __restrict__ degc, const int* __restrict__ part,
    int* __restrict__ rows, int* __restrict__ curs, float* __restrict__ degf)
{
    __shared__ int sh[1024];
    int t = threadIdx.x;
    int i = blockIdx.x * SCAN_BLK + t;
    int v = (i < NN) ? degc[i] : 0;
    sh[t] = v;
    __syncthreads();
    for (int off = 1; off < 1024; off <<= 1) {
        int tmp = (t >= off) ? sh[t - off] : 0;
        __syncthreads();
        sh[t] += tmp;
        __syncthreads();
    }
    int excl = sh[t] - v + part[blockIdx.x];
    if (i < NN) {
        rows[i] = excl;
        curs[i] = excl;
        degf[i] = (float)max(v, 1);
    }
}

// ---------- P2: CSR scatter (blk < 3125) | xb + scores (blk >= 3125) ------------
__global__ __launch_bounds__(256) void k_mid(
    const int* __restrict__ srcp, const int* __restrict__ dstp,
    int* __restrict__ curs, int* __restrict__ csrs,
    const float* __restrict__ x, const float* __restrict__ waS,
    const float* __restrict__ waD, unsigned short* __restrict__ xb,
    float* __restrict__ ssrc, float* __restrict__ sdst)
{
    __shared__ float xs[16 * 64];
    __shared__ unsigned short xsb[16 * 64];
    __shared__ float wl[2 * 256];
    const int t = threadIdx.x;
    if (blockIdx.x < HIST_BLK) {
        const int e = blockIdx.x * 256 + t;
        if (e < EE) {
            const int d = dstp[e];
            const int pos = atomicAdd(&curs[d], 1);
            csrs[pos] = srcp[e];
        }
        return;
    }
    const int n0 = (blockIdx.x - HIST_BLK) * 16;
    {
        const int r = t >> 4, c4 = (t & 15) * 4;
        const float4 v = *(const float4*)&x[(size_t)(n0 + r) * 64 + c4];
        *(float4*)&xs[r * 64 + c4] = v;
        uint2 p;
        p.x = (unsigned int)f2bf(v.x) | ((unsigned int)f2bf(v.y) << 16);
        p.y = (unsigned int)f2bf(v.z) | ((unsigned int)f2bf(v.w) << 16);
        *(uint2*)&xsb[r * 64 + c4] = p;
        wl[t] = waS[t];
        wl[256 + t] = waD[t];
    }
    __syncthreads();
    if (t < 128) {
        const int r = t >> 3, c8 = (t & 7) * 8;
        const uint4 v = *(const uint4*)&xsb[r * 64 + c8];
        *(uint4*)&xb[(size_t)(n0 + r) * 64 + c8] = v;
    }
    {
        const int nl = t >> 4, hh = (t >> 2) & 3, q = t & 3;
        const float* xr = &xs[nl * 64 + q * 16];
        const float* wS = &wl[hh * 64 + q * 16];
        const float* wD = &wl[256 + hh * 64 + q * 16];
        float pS = 0.f, pD = 0.f;
#pragma unroll
        for (int i = 0; i < 16; i++) { pS += xr[i] * wS[i]; pD += xr[i] * wD[i]; }
        pS += __shfl_xor(pS, 1); pS += __shfl_xor(pS, 2);
        pD += __shfl_xor(pD, 1); pD += __shfl_xor(pD, 2);
        if (q == 0) {
            ssrc[(n0 + nl) * 4 + hh] = pS;
            sdst[(n0 + nl) * 4 + hh] = pD;
        }
    }
}

// ---------- K5 (R7 shape): fused attention+hop1; 4 nodes x 2 slots x 8 col-lanes
// ysh stride padded to 72 halfwords: MFMA A ds_read_b128 2-way banks (free).
__global__ __launch_bounds__(256) void k_attn2(
    const unsigned short* __restrict__ xb, const unsigned short* __restrict__ Wt,
    const float* __restrict__ ssrc, const float* __restrict__ sdst,
    const int* __restrict__ rows, const int* __restrict__ degc,
    const float* __restrict__ degf, const int* __restrict__ csrs,
    unsigned short* __restrict__ hop1b, char* __restrict__ outb)
{
    __shared__ unsigned short ysh[4][16][72];     // [head][node][col] bf16, stride 72
    __shared__ float dsh[4][16][66];              // [head][node][col] fp32 (padded)
    const int t = threadIdx.x;
    const int w = t >> 6, lane = t & 63;
    const int nl = (lane >> 4) & 3;
    const int e  = (lane >> 3) & 1;
    const int cl = lane & 7;
    const int n = blockIdx.x * 16 + w * 4 + nl;
    const int start = rows[n], cnt = degc[n];
    int cmax = cnt;
    cmax = max(cmax, __shfl_xor(cmax, 16));
    cmax = max(cmax, __shfl_xor(cmax, 32));
    const float4 sd = *(const float4*)&sdst[n * 4];
    float y0[8], y1[8], y2[8], y3[8], hp[8];
#pragma unroll
    for (int c = 0; c < 8; c++) { y0[c]=0.f; y1[c]=0.f; y2[c]=0.f; y3[c]=0.f; hp[c]=0.f; }
    float d0 = 0.f, d1 = 0.f, d2 = 0.f, d3 = 0.f;
    for (int base = 0; base < cmax; base += 2) {
        const int j = base + e;
        const bool valid = j < cnt;
        const int idx = min(start + j, EE - 1);
        const int s = csrs[idx];
        const float4 ss = *(const float4*)&ssrc[s * 4];
        float e0 = __expf(lrelu(ss.x + sd.x));
        float e1 = __expf(lrelu(ss.y + sd.y));
        float e2 = __expf(lrelu(ss.z + sd.z));
        float e3 = __expf(lrelu(ss.w + sd.w));
        float hw = 1.f;
        if (!valid) { e0 = 0.f; e1 = 0.f; e2 = 0.f; e3 = 0.f; hw = 0.f; }
        d0 += e0; d1 += e1; d2 += e2; d3 += e3;
        const uint4 u = *(const uint4*)&xb[(size_t)s * 64 + cl * 8];
        float xv[8];
        xv[0] = bflo(u.x); xv[1] = bfhi(u.x);
        xv[2] = bflo(u.y); xv[3] = bfhi(u.y);
        xv[4] = bflo(u.z); xv[5] = bfhi(u.z);
        xv[6] = bflo(u.w); xv[7] = bfhi(u.w);
#pragma unroll
        for (int c = 0; c < 8; c++) {
            y0[c] += e0 * xv[c];
            y1[c] += e1 * xv[c];
            y2[c] += e2 * xv[c];
            y3[c] += e3 * xv[c];
            hp[c] += hw * xv[c];
        }
    }
    // reduce over edge-slot bit (xor 8)
#pragma unroll
    for (int c = 0; c < 8; c++) {
        y0[c] += __shfl_xor(y0[c], 8);
        y1[c] += __shfl_xor(y1[c], 8);
        y2[c] += __shfl_xor(y2[c], 8);
        y3[c] += __shfl_xor(y3[c], 8);
        hp[c] += __shfl_xor(hp[c], 8);
    }
    d0 += __shfl_xor(d0, 8);
    d1 += __shfl_xor(d1, 8);
    d2 += __shfl_xor(d2, 8);
    d3 += __shfl_xor(d3, 8);
    if (e == 0) {
        const float i0 = (cnt > 0) ? 1.f / d0 : 0.f;
        const float i1 = (cnt > 0) ? 1.f / d1 : 0.f;
        const float i2 = (cnt > 0) ? 1.f / d2 : 0.f;
        const float i3 = (cnt > 0) ? 1.f / d3 : 0.f;
        const int nloc = w * 4 + nl;
        uint4 p;
        p.x = (unsigned int)f2bf(y0[0]*i0) | ((unsigned int)f2bf(y0[1]*i0) << 16);
        p.y = (unsigned int)f2bf(y0[2]*i0) | ((unsigned int)f2bf(y0[3]*i0) << 16);
        p.z = (unsigned int)f2bf(y0[4]*i0) | ((unsigned int)f2bf(y0[5]*i0) << 16);
        p.w = (unsigned int)f2bf(y0[6]*i0) | ((unsigned int)f2bf(y0[7]*i0) << 16);
        *(uint4*)&ysh[0][nloc][cl * 8] = p;
        p.x = (unsigned int)f2bf(y1[0]*i1) | ((unsigned int)f2bf(y1[1]*i1) << 16);
        p.y = (unsigned int)f2bf(y1[2]*i1) | ((unsigned int)f2bf(y1[3]*i1) << 16);
        p.z = (unsigned int)f2bf(y1[4]*i1) | ((unsigned int)f2bf(y1[5]*i1) << 16);
        p.w = (unsigned int)f2bf(y1[6]*i1) | ((unsigned int)f2bf(y1[7]*i1) << 16);
        *(uint4*)&ysh[1][nloc][cl * 8] = p;
        p.x = (unsigned int)f2bf(y2[0]*i2) | ((unsigned int)f2bf(y2[1]*i2) << 16);
        p.y = (unsigned int)f2bf(y2[2]*i2) | ((unsigned int)f2bf(y2[3]*i2) << 16);
        p.z = (unsigned int)f2bf(y2[4]*i2) | ((unsigned int)f2bf(y2[5]*i2) << 16);
        p.w = (unsigned int)f2bf(y2[6]*i2) | ((unsigned int)f2bf(y2[7]*i2) << 16);
        *(uint4*)&ysh[2][nloc][cl * 8] = p;
        p.x = (unsigned int)f2bf(y3[0]*i3) | ((unsigned int)f2bf(y3[1]*i3) << 16);
        p.y = (unsigned int)f2bf(y3[2]*i3) | ((unsigned int)f2bf(y3[3]*i3) << 16);
        p.z = (unsigned int)f2bf(y3[4]*i3) | ((unsigned int)f2bf(y3[5]*i3) << 16);
        p.w = (unsigned int)f2bf(y3[6]*i3) | ((unsigned int)f2bf(y3[7]*i3) << 16);
        *(uint4*)&ysh[3][nloc][cl * 8] = p;
        const float iv = 1.f / degf[n];
        p.x = (unsigned int)f2bf(hp[0]*iv) | ((unsigned int)f2bf(hp[1]*iv) << 16);
        p.y = (unsigned int)f2bf(hp[2]*iv) | ((unsigned int)f2bf(hp[3]*iv) << 16);
        p.z = (unsigned int)f2bf(hp[4]*iv) | ((unsigned int)f2bf(hp[5]*iv) << 16);
        p.w = (unsigned int)f2bf(hp[6]*iv) | ((unsigned int)f2bf(hp[7]*iv) << 16);
        *(uint4*)&hop1b[(size_t)n * 64 + cl * 8] = p;
    }
    __syncthreads();
    // MFMA: wave w computes head w: D[16 nodes x 64] = Y_w @ W_w
    {
        const int m = lane & 15, quad = lane >> 4;
        const bf16x8 a0 = *(const bf16x8*)&ysh[w][m][quad * 8];
        const bf16x8 a1 = *(const bf16x8*)&ysh[w][m][32 + quad * 8];
        f32x4 acc[4] = {{0.f,0.f,0.f,0.f},{0.f,0.f,0.f,0.f},{0.f,0.f,0.f,0.f},{0.f,0.f,0.f,0.f}};
#pragma unroll
        for (int ot = 0; ot < 4; ot++) {
            const unsigned short* wp = Wt + w * 4096 + (ot * 16 + m) * 64 + quad * 8;
            const bf16x8 b0 = *(const bf16x8*)wp;
            const bf16x8 b1 = *(const bf16x8*)(wp + 32);
            acc[ot] = __builtin_amdgcn_mfma_f32_16x16x32_bf16(a0, b0, acc[ot], 0, 0, 0);
            acc[ot] = __builtin_amdgcn_mfma_f32_16x16x32_bf16(a1, b1, acc[ot], 0, 0, 0);
        }
#pragma unroll
        for (int ot = 0; ot < 4; ot++)
#pragma unroll
            for (int r = 0; r < 4; r++)
                dsh[w][quad * 4 + r][ot * 16 + m] = acc[ot][r];
    }
    __syncthreads();
    // head mean -> bf16 local into first 128B of each 256B d_out slot
    {
        const int n2 = t >> 4, c4 = (t & 15) * 4;
        float o0 = 0.25f * (dsh[0][n2][c4+0] + dsh[1][n2][c4+0] + dsh[2][n2][c4+0] + dsh[3][n2][c4+0]);
        float o1 = 0.25f * (dsh[0][n2][c4+1] + dsh[1][n2][c4+1] + dsh[2][n2][c4+1] + dsh[3][n2][c4+1]);
        float o2 = 0.25f * (dsh[0][n2][c4+2] + dsh[1][n2][c4+2] + dsh[2][n2][c4+2] + dsh[3][n2][c4+2]);
        float o3 = 0.25f * (dsh[0][n2][c4+3] + dsh[1][n2][c4+3] + dsh[2][n2][c4+3] + dsh[3][n2][c4+3]);
        uint2 p;
        p.x = (unsigned int)f2bf(o0) | ((unsigned int)f2bf(o1) << 16);
        p.y = (unsigned int)f2bf(o2) | ((unsigned int)f2bf(o3) << 16);
        *(uint2*)(outb + ((size_t)(blockIdx.x * 16 + n2)) * 256 + (t & 15) * 8) = p;
    }
}

// ---------- K6: second mean hop — 8 lanes per edge row ----------
__global__ __launch_bounds__(256) void k_hop(
    const unsigned short* __restrict__ xin, const int* __restrict__ rows,
    const int* __restrict__ degc, const float* __restrict__ degf,
    const int* __restrict__ csrs, unsigned short* __restrict__ out_b)
{
    const int lane = threadIdx.x & 63;
    const int n = blockIdx.x * 4 + (threadIdx.x >> 6);
    if (n >= NN) return;
    const int start = rows[n], cnt = degc[n];
    const int g = lane >> 3;
    const int c8 = (lane & 7) * 8;
    float a0=0.f,a1=0.f,a2=0.f,a3=0.f,a4=0.f,a5=0.f,a6=0.f,a7=0.f;
    for (int j = g; j < cnt; j += 8) {
        const int s = csrs[start + j];
        const uint4 u = *(const uint4*)&xin[(size_t)s * 64 + c8];
        a0 += bflo(u.x); a1 += bfhi(u.x);
        a2 += bflo(u.y); a3 += bfhi(u.y);
        a4 += bflo(u.z); a5 += bfhi(u.z);
        a6 += bflo(u.w); a7 += bfhi(u.w);
    }
#pragma unroll
    for (int off = 8; off < 64; off <<= 1) {
        a0 += __shfl_xor(a0, off); a1 += __shfl_xor(a1, off);
        a2 += __shfl_xor(a2, off); a3 += __shfl_xor(a3, off);
        a4 += __shfl_xor(a4, off); a5 += __shfl_xor(a5, off);
        a6 += __shfl_xor(a6, off); a7 += __shfl_xor(a7, off);
    }
    if (lane < 8) {
        const float inv = 1.f / degf[n];
        uint4 p;
        p.x = (unsigned int)f2bf(a0 * inv) | ((unsigned int)f2bf(a1 * inv) << 16);
        p.y = (unsigned int)f2bf(a2 * inv) | ((unsigned int)f2bf(a3 * inv) << 16);
        p.z = (unsigned int)f2bf(a4 * inv) | ((unsigned int)f2bf(a5 * inv) << 16);
        p.w = (unsigned int)f2bf(a6 * inv) | ((unsigned int)f2bf(a7 * inv) << 16);
        *(uint4*)&out_b[(size_t)n * 64 + c8] = p;
    }
}

// ---------- K9: MFMA out = cat(localb,hop2b) @ Wcat + bc; 64 nodes/block -------
__global__ __launch_bounds__(256) void k_final(
    const unsigned short* __restrict__ Wcat, const float* __restrict__ bc,
    const unsigned short* __restrict__ hop2b, float* __restrict__ outp)
{
    __shared__ float os[64 * 68];
    __shared__ float bcl[64];
    const int t = threadIdx.x;
    const int n0 = blockIdx.x * 64;
    if (t < 64) bcl[t] = bc[t];
    const int w = t >> 6, lane = t & 63, m = lane & 15, quad = lane >> 4;
    const int node = n0 + w * 16 + m;
    const int nld = min(node, NN - 1);
    const unsigned short* lrow = (const unsigned short*)((const char*)outp + (size_t)nld * 256);
    const unsigned short* grow = &hop2b[(size_t)nld * 64];
    const bf16x8 a0 = *(const bf16x8*)&lrow[quad * 8];
    const bf16x8 a1 = *(const bf16x8*)&lrow[32 + quad * 8];
    const bf16x8 a2 = *(const bf16x8*)&grow[quad * 8];
    const bf16x8 a3 = *(const bf16x8*)&grow[32 + quad * 8];
    f32x4 acc[4] = {{0.f,0.f,0.f,0.f},{0.f,0.f,0.f,0.f},{0.f,0.f,0.f,0.f},{0.f,0.f,0.f,0.f}};
#pragma unroll
    for (int ot = 0; ot < 4; ot++) {
        const unsigned short* wp = Wcat + (ot * 16 + m) * 128 + quad * 8;
        const bf16x8 b0 = *(const bf16x8*)wp;
        const bf16x8 b1 = *(const bf16x8*)(wp + 32);
        const bf16x8 b2 = *(const bf16x8*)(wp + 64);
        const bf16x8 b3 = *(const bf16x8*)(wp + 96);
        acc[ot] = __builtin_amdgcn_mfma_f32_16x16x32_bf16(a0, b0, acc[ot], 0, 0, 0);
        acc[ot] = __builtin_amdgcn_mfma_f32_16x16x32_bf16(a1, b1, acc[ot], 0, 0, 0);
        acc[ot] = __builtin_amdgcn_mfma_f32_16x16x32_bf16(a2, b2, acc[ot], 0, 0, 0);
        acc[ot] = __builtin_amdgcn_mfma_f32_16x16x32_bf16(a3, b3, acc[ot], 0, 0, 0);
    }
    __syncthreads();
#pragma unroll
    for (int ot = 0; ot < 4; ot++)
#pragma unroll
        for (int r = 0; r < 4; r++)
            os[(w * 16 + quad * 4 + r) * 68 + ot * 16 + m] = acc[ot][r] + bcl[ot * 16 + m];
    __syncthreads();
#pragma unroll
    for (int p = 0; p < 4; p++) {
        const int idx = p * 256 + t;
        const int row = idx >> 4, f4 = idx & 15;
        if (n0 + row < NN)
            *(float4*)&outp[(size_t)(n0 + row) * 64 + f4 * 4] = *(const float4*)&os[row * 68 + f4 * 4];
    }
}

extern "C" void kernel_launch(void* const* d_in, const int* in_sizes, int n_in,
                              void* d_out, int out_size, void* d_ws, size_t ws_size,
                              hipStream_t stream)
{
    const float* x    = (const float*)d_in[0];
    const int*   ei   = (const int*)d_in[1];
    const int*   srcp = ei;
    const int*   dstp = ei + EE;
    const float* Watt = (const float*)d_in[2];
    const float* asrc = (const float*)d_in[3];
    const float* adst = (const float*)d_in[4];
    const float* Wg   = (const float*)d_in[5];
    const float* bg   = (const float*)d_in[6];
    const float* Ww   = (const float*)d_in[7];
    const float* bw   = (const float*)d_in[8];
    float* outp = (float*)d_out;

    if (ws_size < WS_NEEDED) return;

    char* ws = (char*)d_ws;
    unsigned short* xb    = (unsigned short*)(ws + OFF_XB);
    unsigned short* hop1b = (unsigned short*)(ws + OFF_HOP1);
    unsigned short* hop2b = (unsigned short*)(ws + OFF_HOP2);
    float* ssrc = (float*)(ws + OFF_SSRC);
    float* sdst = (float*)(ws + OFF_SDST);
    int*   degc = (int*)(ws + OFF_DEGC);
    int*   rows = (int*)(ws + OFF_ROWS);
    int*   curs = (int*)(ws + OFF_CURS);
    float* degf = (float*)(ws + OFF_DEGF);
    int*   part = (int*)(ws + OFF_PART);
    int*   csrs = (int*)(ws + OFF_CSRS);
    unsigned short* Wcat = (unsigned short*)(ws + OFF_WCAT);
    float* bc   = (float*)(ws + OFF_BCOMB);
    unsigned short* Wt = (unsigned short*)(ws + OFF_WT);
    float* waS  = (float*)(ws + OFF_WAS);
    float* waD  = (float*)(ws + OFF_WAD);

    hipMemsetAsync(degc, 0, NN * sizeof(int), stream);
    k_pre<<<24 + HIST_BLK, 256, 0, stream>>>(Watt, asrc, adst, Wg, bg, Ww, bw,
                                             dstp, Wt, waS, waD, Wcat, bc, degc);
    k_scan_a<<<SCAN_NBLK, 1024, 0, stream>>>(degc, part);
    k_scan_b<<<1, 128, 0, stream>>>(part);
    k_scan_c<<<SCAN_NBLK, 1024, 0, stream>>>(degc, part, rows, curs, degf);
    k_mid<<<HIST_BLK + KH_BLK, 256, 0, stream>>>(srcp, dstp, curs, csrs,
                                                 x, waS, waD, xb, ssrc, sdst);
    k_attn2<<<NN / 16, 256, 0, stream>>>(xb, Wt, ssrc, sdst, rows, degc, degf, csrs,
                                         hop1b, (char*)d_out);
    k_hop<<<NN / 4, 256, 0, stream>>>(hop1b, rows, degc, degf, csrs, hop2b);
    k_final<<<(NN + 63) / 64, 256, 0, stream>>>(Wcat, bc, hop2b, outp);
}